// Round 1
// baseline (1272.344 us; speedup 1.0000x reference)
//
#include <hip/hip_runtime.h>
#include <hip/hip_bf16.h>
#include <cmath>

// Problem constants
#define NB 8
#define CIN_C 512
#define HW 4096
#define PP 1024    // pooled pixels
#define C8 64
#define C2 256

// ---------------------------------------------------------------------------
// Tiled fp32 GEMM: Y[n][k][p] = sum_c W[k][c] * X[n][c][p] + bias[k]
// MODE 0: normal output  [n][KT][4096]
// MODE 1: transposed out [n][4096][64]   (theta)
// MODE 2: residual: Y = gamma*(acc+bias) + resid, layout [n][KT][4096]
// ---------------------------------------------------------------------------
template<int CIN, int MODE>
__global__ __launch_bounds__(256) void gemm_k(
    const float* __restrict__ Wm, const float* __restrict__ bias,
    const float* __restrict__ X, float* __restrict__ Y,
    const float* __restrict__ resid, const float* __restrict__ gam)
{
    __shared__ float Ws[64][17];   // [k][c-chunk], +1 pad
    __shared__ float Xs[16][68];   // [c-chunk][p], pad to 68 (272B row, 16B-aligned)

    const int tid = threadIdx.x;
    const int tx = tid & 15;       // p-group
    const int ty = tid >> 4;       // k-group
    const int n  = blockIdx.z;
    const int k0 = blockIdx.y * 64;
    const int p0 = blockIdx.x * 64;
    const int KT = gridDim.y * 64;

    const float* Xn = X + (size_t)n * CIN * HW;
    const int lrow = tid >> 6, lcol = tid & 63;

    float acc[4][4] = {};

    for (int c0 = 0; c0 < CIN; c0 += 16) {
#pragma unroll
        for (int it = 0; it < 4; ++it)
            Ws[ty + 16 * it][tx] = Wm[(size_t)(k0 + ty + 16 * it) * CIN + (c0 + tx)];
#pragma unroll
        for (int it = 0; it < 4; ++it)
            Xs[lrow + 4 * it][lcol] = Xn[(size_t)(c0 + lrow + 4 * it) * HW + p0 + lcol];
        __syncthreads();
#pragma unroll
        for (int cc = 0; cc < 16; ++cc) {
            float4 xv = *(const float4*)&Xs[cc][tx * 4];
            float wv0 = Ws[ty * 4 + 0][cc];
            float wv1 = Ws[ty * 4 + 1][cc];
            float wv2 = Ws[ty * 4 + 2][cc];
            float wv3 = Ws[ty * 4 + 3][cc];
            acc[0][0] += wv0 * xv.x; acc[0][1] += wv0 * xv.y; acc[0][2] += wv0 * xv.z; acc[0][3] += wv0 * xv.w;
            acc[1][0] += wv1 * xv.x; acc[1][1] += wv1 * xv.y; acc[1][2] += wv1 * xv.z; acc[1][3] += wv1 * xv.w;
            acc[2][0] += wv2 * xv.x; acc[2][1] += wv2 * xv.y; acc[2][2] += wv2 * xv.z; acc[2][3] += wv2 * xv.w;
            acc[3][0] += wv3 * xv.x; acc[3][1] += wv3 * xv.y; acc[3][2] += wv3 * xv.z; acc[3][3] += wv3 * xv.w;
        }
        __syncthreads();
    }

    if (MODE == 0) {
#pragma unroll
        for (int i = 0; i < 4; ++i) {
            int k = k0 + ty * 4 + i;
            float b = bias[k];
            float4 v = make_float4(acc[i][0] + b, acc[i][1] + b, acc[i][2] + b, acc[i][3] + b);
            *(float4*)&Y[((size_t)(n * KT + k)) * HW + p0 + tx * 4] = v;
        }
    } else if (MODE == 1) {
        float b0 = bias[k0 + ty * 4 + 0];
        float b1 = bias[k0 + ty * 4 + 1];
        float b2 = bias[k0 + ty * 4 + 2];
        float b3 = bias[k0 + ty * 4 + 3];
#pragma unroll
        for (int j = 0; j < 4; ++j) {
            int p = p0 + tx * 4 + j;
            float4 v = make_float4(acc[0][j] + b0, acc[1][j] + b1, acc[2][j] + b2, acc[3][j] + b3);
            *(float4*)&Y[((size_t)(n * HW + p)) * 64 + (k0 + ty * 4)] = v;
        }
    } else {
        float g0 = gam[0];
#pragma unroll
        for (int i = 0; i < 4; ++i) {
            int k = k0 + ty * 4 + i;
            float b = bias[k];
            size_t off = ((size_t)(n * KT + k)) * HW + p0 + tx * 4;
            float4 r = *(const float4*)&resid[off];
            float4 v = make_float4(g0 * (acc[i][0] + b) + r.x,
                                   g0 * (acc[i][1] + b) + r.y,
                                   g0 * (acc[i][2] + b) + r.z,
                                   g0 * (acc[i][3] + b) + r.w);
            *(float4*)&Y[off] = v;
        }
    }
}

// ---------------------------------------------------------------------------
// phi maxpool: [n][64][64x64] -> [n][64][32x32]
// ---------------------------------------------------------------------------
__global__ __launch_bounds__(256) void pool_phi_k(const float* __restrict__ in,
                                                  float* __restrict__ out)
{
    int gid = blockIdx.x * 256 + threadIdx.x;   // 8*64*1024 = 524288
    int pidx = gid & 1023;
    int ph = pidx >> 5, pw = pidx & 31;
    int nk = gid >> 10;                          // n*64 + k
    size_t base = (size_t)nk * HW + (size_t)(2 * ph) * 64 + 2 * pw;
    float a = in[base], b = in[base + 1], c = in[base + 64], d = in[base + 65];
    out[gid] = fmaxf(fmaxf(a, b), fmaxf(c, d));
}

// ---------------------------------------------------------------------------
// g maxpool + transpose: [n][256][64x64] -> g_t [n][1024][256]
// one block per (n, ph); LDS transpose for coalesced writes
// ---------------------------------------------------------------------------
__global__ __launch_bounds__(256) void pool_g_k(const float* __restrict__ in,
                                                float* __restrict__ out)
{
    __shared__ float t[32][257];
    const int tid = threadIdx.x;
    const int n = blockIdx.x >> 5;
    const int ph = blockIdx.x & 31;

#pragma unroll
    for (int oi = 0; oi < 32; ++oi) {
        int idx = tid + 256 * oi;       // 0..8191 over [c][pw]
        int c = idx >> 5, pw = idx & 31;
        size_t base = ((size_t)(n * 256 + c)) * HW + (size_t)(2 * ph) * 64 + 2 * pw;
        float a = in[base], b = in[base + 1], e = in[base + 64], d = in[base + 65];
        t[pw][c] = fmaxf(fmaxf(a, b), fmaxf(e, d));
    }
    __syncthreads();
#pragma unroll
    for (int oi = 0; oi < 32; ++oi) {
        int idx = tid + 256 * oi;       // over [pw][c]
        int c = idx & 255, pw = idx >> 8;
        out[((size_t)(n * PP) + ph * 32 + pw) * 256 + c] = t[pw][c];
    }
}

// ---------------------------------------------------------------------------
// Attention: per block = (n, 16-query tile)
//  energy[q][p] = dot(theta_t[q], phi[:,p]); softmax over p (1024);
//  out[c][q] = sum_p g_t[p][c] * att[q][p]  -> attn [n][256][4096]
// ---------------------------------------------------------------------------
__global__ __launch_bounds__(256) void attn_k(const float* __restrict__ theta_t,
                                              const float* __restrict__ phi_p,
                                              const float* __restrict__ g_t,
                                              float* __restrict__ attn_out)
{
    __shared__ float theta_s[16][64];
    __shared__ float att[16][1025];
    __shared__ float red[16][16];
    __shared__ float m_s[16], inv_s[16];

    const int tid = threadIdx.x;
    const int n = blockIdx.y;
    const int q0 = blockIdx.x * 16;

    // Phase A: load theta tile [16 q][64 k]
#pragma unroll
    for (int it = 0; it < 4; ++it) {
        int idx = tid + 256 * it;
        int q = idx >> 6, k = idx & 63;
        theta_s[q][k] = theta_t[((size_t)(n * HW) + (q0 + q)) * 64 + k];
    }
    __syncthreads();

    // Phase B: energy
    const float* phiB = phi_p + (size_t)n * 64 * PP;
    for (int pp = 0; pp < 4; ++pp) {
        int p = pp * 256 + tid;
        float e[16] = {};
#pragma unroll
        for (int k0 = 0; k0 < 64; k0 += 4) {
            float v0 = phiB[(k0 + 0) * PP + p];
            float v1 = phiB[(k0 + 1) * PP + p];
            float v2 = phiB[(k0 + 2) * PP + p];
            float v3 = phiB[(k0 + 3) * PP + p];
#pragma unroll
            for (int q = 0; q < 16; ++q) {
                float4 t4 = *(const float4*)&theta_s[q][k0];
                e[q] += t4.x * v0 + t4.y * v1 + t4.z * v2 + t4.w * v3;
            }
        }
#pragma unroll
        for (int q = 0; q < 16; ++q) att[q][p] = e[q];
    }
    __syncthreads();

    // Softmax (store unnormalized exp; 1/l folded into epilogue)
    const int qi = tid & 15, pg = tid >> 4;
    float mx = -1e30f;
#pragma unroll 16
    for (int i = 0; i < 64; ++i) mx = fmaxf(mx, att[qi][pg * 64 + i]);
    red[pg][qi] = mx;
    __syncthreads();
    if (tid < 16) {
        float m = red[0][tid];
#pragma unroll
        for (int j = 1; j < 16; ++j) m = fmaxf(m, red[j][tid]);
        m_s[tid] = m;
    }
    __syncthreads();
    {
        float m = m_s[qi];
        float s = 0.f;
#pragma unroll 16
        for (int i = 0; i < 64; ++i) {
            float v = __expf(att[qi][pg * 64 + i] - m);
            att[qi][pg * 64 + i] = v;
            s += v;
        }
        red[pg][qi] = s;
    }
    __syncthreads();
    if (tid < 16) {
        float s = 0.f;
#pragma unroll
        for (int j = 0; j < 16; ++j) s += red[j][tid];
        inv_s[tid] = 1.0f / s;
    }
    __syncthreads();

    // Phase C: out[c][q] partial sums; wave w covers p in [256w, 256w+256)
    const int w = tid >> 6, lane = tid & 63;
    const int cbase = lane * 4;
    const float* gB = g_t + (size_t)n * PP * 256;
    float o[16][4] = {};
    for (int p = w * 256; p < w * 256 + 256; ++p) {
        float4 gv = *(const float4*)&gB[(size_t)p * 256 + cbase];
#pragma unroll
        for (int q = 0; q < 16; ++q) {
            float a = att[q][p];
            o[q][0] += a * gv.x; o[q][1] += a * gv.y;
            o[q][2] += a * gv.z; o[q][3] += a * gv.w;
        }
    }
    __syncthreads();   // all waves done reading att; safe to alias

    float* red2 = &att[0][0];   // [4 w][16 q][256 c] = 16384 floats <= 16*1025
#pragma unroll
    for (int q = 0; q < 16; ++q) {
        float4 v = make_float4(o[q][0], o[q][1], o[q][2], o[q][3]);
        *(float4*)&red2[((w * 16 + q) * 256) + cbase] = v;
    }
    __syncthreads();

    // Final: thread = c; sum 4 wave partials, scale by inv, store
    {
        int c = tid;
        float vals[16];
#pragma unroll
        for (int q = 0; q < 16; ++q) {
            float v = red2[((0 * 16 + q) * 256) + c]
                    + red2[((1 * 16 + q) * 256) + c]
                    + red2[((2 * 16 + q) * 256) + c]
                    + red2[((3 * 16 + q) * 256) + c];
            vals[q] = v * inv_s[q];
        }
        size_t base = ((size_t)(n * 256 + c)) * HW + q0;
#pragma unroll
        for (int j = 0; j < 4; ++j) {
            float4 v = make_float4(vals[4 * j + 0], vals[4 * j + 1],
                                   vals[4 * j + 2], vals[4 * j + 3]);
            *(float4*)&attn_out[base + 4 * j] = v;
        }
    }
}

// ---------------------------------------------------------------------------
extern "C" void kernel_launch(void* const* d_in, const int* in_sizes, int n_in,
                              void* d_out, int out_size, void* d_ws, size_t ws_size,
                              hipStream_t stream)
{
    const float* x       = (const float*)d_in[0];
    const float* theta_w = (const float*)d_in[1];
    const float* theta_b = (const float*)d_in[2];
    const float* phi_w   = (const float*)d_in[3];
    const float* phi_b   = (const float*)d_in[4];
    const float* g_w     = (const float*)d_in[5];
    const float* g_b     = (const float*)d_in[6];
    const float* out_w   = (const float*)d_in[7];
    const float* out_b   = (const float*)d_in[8];
    const float* gamma   = (const float*)d_in[9];
    float* out = (float*)d_out;

    float* ws = (float*)d_ws;
    float* theta_t = ws;                       // [8][4096][64]   2,097,152
    float* phi_p   = ws + 2097152;             // [8][64][1024]     524,288
    float* g_t     = ws + 2621440;             // [8][1024][256]  2,097,152
    float* D       = ws + 4718592;             // scratch 8,388,608 floats
                                               // (phi_full -> g_full -> attn)

    // 1) theta = x . theta_w^T  (transposed output)
    gemm_k<512, 1><<<dim3(64, 1, NB), 256, 0, stream>>>(theta_w, theta_b, x, theta_t, nullptr, nullptr);
    // 2) phi full -> D
    gemm_k<512, 0><<<dim3(64, 1, NB), 256, 0, stream>>>(phi_w, phi_b, x, D, nullptr, nullptr);
    // 3) pool phi -> phi_p
    pool_phi_k<<<dim3(2048), 256, 0, stream>>>(D, phi_p);
    // 4) g full -> D
    gemm_k<512, 0><<<dim3(64, 4, NB), 256, 0, stream>>>(g_w, g_b, x, D, nullptr, nullptr);
    // 5) pool+transpose g -> g_t
    pool_g_k<<<dim3(256), 256, 0, stream>>>(D, g_t);
    // 6) attention -> D  (attn [8][256][4096])
    attn_k<<<dim3(256, NB), 256, 0, stream>>>(theta_t, phi_p, g_t, D);
    // 7) final conv + gamma*out + x -> d_out
    gemm_k<256, 2><<<dim3(64, 8, NB), 256, 0, stream>>>(out_w, out_b, D, out, x, gamma);
}

// Round 2
// 523.526 us; speedup vs baseline: 2.4303x; 2.4303x over previous
//
#include <hip/hip_runtime.h>
#include <hip/hip_bf16.h>
#include <cmath>

// Problem constants
#define NB 8
#define CIN_C 512
#define HW 4096
#define PP 1024    // pooled pixels
#define C8 64
#define C2 256

typedef _Float16 half8 __attribute__((ext_vector_type(8)));
typedef _Float16 half4 __attribute__((ext_vector_type(4)));
typedef _Float16 half2t __attribute__((ext_vector_type(2)));
typedef float f32x4 __attribute__((ext_vector_type(4)));

// ---------------------------------------------------------------------------
// Tiled fp32 GEMM: Y[n][k][p] = sum_c W[k][c] * X[n][c][p] + bias[k]
// MODE 0: normal output  [n][KT][4096] fp32
// MODE 1: transposed out [n][4096][64] fp16   (theta)
// MODE 2: residual: Y = gamma*(acc+bias) + resid, layout [n][KT][4096] fp32
// ---------------------------------------------------------------------------
template<int CIN, int MODE>
__global__ __launch_bounds__(256) void gemm_k(
    const float* __restrict__ Wm, const float* __restrict__ bias,
    const float* __restrict__ X, void* __restrict__ Yv,
    const float* __restrict__ resid, const float* __restrict__ gam)
{
    __shared__ float Ws[64][17];
    __shared__ float Xs[16][68];

    const int tid = threadIdx.x;
    const int tx = tid & 15;
    const int ty = tid >> 4;
    const int n  = blockIdx.z;
    const int k0 = blockIdx.y * 64;
    const int p0 = blockIdx.x * 64;
    const int KT = gridDim.y * 64;

    const float* Xn = X + (size_t)n * CIN * HW;
    const int lrow = tid >> 6, lcol = tid & 63;

    float acc[4][4] = {};

    for (int c0 = 0; c0 < CIN; c0 += 16) {
#pragma unroll
        for (int it = 0; it < 4; ++it)
            Ws[ty + 16 * it][tx] = Wm[(size_t)(k0 + ty + 16 * it) * CIN + (c0 + tx)];
#pragma unroll
        for (int it = 0; it < 4; ++it)
            Xs[lrow + 4 * it][lcol] = Xn[(size_t)(c0 + lrow + 4 * it) * HW + p0 + lcol];
        __syncthreads();
#pragma unroll
        for (int cc = 0; cc < 16; ++cc) {
            float4 xv = *(const float4*)&Xs[cc][tx * 4];
            float wv0 = Ws[ty * 4 + 0][cc];
            float wv1 = Ws[ty * 4 + 1][cc];
            float wv2 = Ws[ty * 4 + 2][cc];
            float wv3 = Ws[ty * 4 + 3][cc];
            acc[0][0] += wv0 * xv.x; acc[0][1] += wv0 * xv.y; acc[0][2] += wv0 * xv.z; acc[0][3] += wv0 * xv.w;
            acc[1][0] += wv1 * xv.x; acc[1][1] += wv1 * xv.y; acc[1][2] += wv1 * xv.z; acc[1][3] += wv1 * xv.w;
            acc[2][0] += wv2 * xv.x; acc[2][1] += wv2 * xv.y; acc[2][2] += wv2 * xv.z; acc[2][3] += wv2 * xv.w;
            acc[3][0] += wv3 * xv.x; acc[3][1] += wv3 * xv.y; acc[3][2] += wv3 * xv.z; acc[3][3] += wv3 * xv.w;
        }
        __syncthreads();
    }

    if (MODE == 0) {
        float* Y = (float*)Yv;
#pragma unroll
        for (int i = 0; i < 4; ++i) {
            int k = k0 + ty * 4 + i;
            float b = bias[k];
            float4 v = make_float4(acc[i][0] + b, acc[i][1] + b, acc[i][2] + b, acc[i][3] + b);
            *(float4*)&Y[((size_t)(n * KT + k)) * HW + p0 + tx * 4] = v;
        }
    } else if (MODE == 1) {
        _Float16* Yh = (_Float16*)Yv;
        float b0 = bias[k0 + ty * 4 + 0];
        float b1 = bias[k0 + ty * 4 + 1];
        float b2 = bias[k0 + ty * 4 + 2];
        float b3 = bias[k0 + ty * 4 + 3];
#pragma unroll
        for (int j = 0; j < 4; ++j) {
            int p = p0 + tx * 4 + j;
            half4 v;
            v[0] = (_Float16)(acc[0][j] + b0);
            v[1] = (_Float16)(acc[1][j] + b1);
            v[2] = (_Float16)(acc[2][j] + b2);
            v[3] = (_Float16)(acc[3][j] + b3);
            *(half4*)&Yh[((size_t)(n * HW + p)) * 64 + (k0 + ty * 4)] = v;
        }
    } else {
        float* Y = (float*)Yv;
        float g0 = gam[0];
#pragma unroll
        for (int i = 0; i < 4; ++i) {
            int k = k0 + ty * 4 + i;
            float b = bias[k];
            size_t off = ((size_t)(n * KT + k)) * HW + p0 + tx * 4;
            float4 r = *(const float4*)&resid[off];
            float4 v = make_float4(g0 * (acc[i][0] + b) + r.x,
                                   g0 * (acc[i][1] + b) + r.y,
                                   g0 * (acc[i][2] + b) + r.z,
                                   g0 * (acc[i][3] + b) + r.w);
            *(float4*)&Y[off] = v;
        }
    }
}

// ---------------------------------------------------------------------------
// phi maxpool + transpose: [n][64][64x64] fp32 -> [n][1024 p][64 k] fp16
// block per (n, ph): pooled row strip of 32 pw, all 64 k
// ---------------------------------------------------------------------------
__global__ __launch_bounds__(256) void pool_phi_t_k(const float* __restrict__ in,
                                                    _Float16* __restrict__ out)
{
    __shared__ _Float16 t[32][72];   // [pw][k], padded
    const int tid = threadIdx.x;
    const int n  = blockIdx.x >> 5;
    const int ph = blockIdx.x & 31;

#pragma unroll
    for (int it = 0; it < 8; ++it) {
        int idx = tid + 256 * it;        // 2048: [k][pw]
        int k = idx >> 5, pw = idx & 31;
        size_t base = ((size_t)(n * 64 + k)) * HW + (size_t)(2 * ph) * 64 + 2 * pw;
        float a = in[base], b = in[base + 1], c = in[base + 64], d = in[base + 65];
        t[pw][k] = (_Float16)fmaxf(fmaxf(a, b), fmaxf(c, d));
    }
    __syncthreads();
#pragma unroll
    for (int it = 0; it < 8; ++it) {
        int idx = tid + 256 * it;        // [pw][k]
        int pw = idx >> 6, k = idx & 63;
        out[((size_t)(n * PP) + ph * 32 + pw) * 64 + k] = t[pw][k];
    }
}

// ---------------------------------------------------------------------------
// g maxpool: [n][256][64x64] fp32 -> [n][256 c][1024 p] fp16 (no transpose)
// ---------------------------------------------------------------------------
__global__ __launch_bounds__(256) void pool_g_h_k(const float* __restrict__ in,
                                                  _Float16* __restrict__ out)
{
    int gid = blockIdx.x * 256 + threadIdx.x;    // 8*256*1024 = 2097152
    int p = gid & 1023;
    int ph = p >> 5, pw = p & 31;
    int nc = gid >> 10;                          // n*256 + c
    size_t base = (size_t)nc * HW + (size_t)(2 * ph) * 64 + 2 * pw;
    float a = in[base], b = in[base + 1], c = in[base + 64], d = in[base + 65];
    out[gid] = (_Float16)fmaxf(fmaxf(a, b), fmaxf(c, d));
}

// ---------------------------------------------------------------------------
// MFMA attention. Block = (n, 32-query tile), 4 waves.
//  E^T[p][q] via mfma(A=phi_t[p][k], B=theta^T) -> LDS P[32 q][1024 p] fp16
//  softmax in place over p; PV: O^T[c][q] via mfma(A=g[c][p], B=P^T from LDS)
//  out: attn [n][256 c][4096 q] fp32, with 1/l folded in.
// Fragment layouts (16x16x32): A[m=lane&15][k=quad*8+j]; B[k=quad*8+j][col=lane&15];
// C: col=lane&15, row=quad*4+reg.
// ---------------------------------------------------------------------------
__global__ __launch_bounds__(256, 2) void attn_mfma_k(
    const _Float16* __restrict__ theta16,   // [n][4096][64]
    const _Float16* __restrict__ phi16,     // [n][1024][64]
    const _Float16* __restrict__ g16,       // [n][256][1024]
    float* __restrict__ attn_out)           // [n][256][4096]
{
    __shared__ _Float16 P[32][1032];
    __shared__ float red[8][32];
    __shared__ float m_s[32];
    __shared__ float inv_s[32];

    const int tid  = threadIdx.x;
    const int wave = tid >> 6;
    const int lane = tid & 63;
    const int quad = lane >> 4;
    const int lq   = lane & 15;
    const int n  = blockIdx.y;
    const int q0 = blockIdx.x * 32;

    // --- theta B-fragments (held in regs for whole E phase) ---
    half8 tb[2][2];
#pragma unroll
    for (int qt = 0; qt < 2; ++qt)
#pragma unroll
        for (int kb = 0; kb < 2; ++kb)
            tb[qt][kb] = *(const half8*)&theta16[((size_t)(n * HW) + q0 + qt * 16 + lq) * 64 + kb * 32 + quad * 8];

    // --- Energy phase: wave handles p in [wave*256, wave*256+256) ---
    const _Float16* phiN = phi16 + (size_t)n * PP * 64;
#pragma unroll 4
    for (int pt = 0; pt < 16; ++pt) {
        int pb = wave * 256 + pt * 16;
        half8 a0 = *(const half8*)&phiN[(size_t)(pb + lq) * 64 + quad * 8];
        half8 a1 = *(const half8*)&phiN[(size_t)(pb + lq) * 64 + 32 + quad * 8];
#pragma unroll
        for (int qt = 0; qt < 2; ++qt) {
            f32x4 c = {0.f, 0.f, 0.f, 0.f};
            c = __builtin_amdgcn_mfma_f32_16x16x32_f16(a0, tb[qt][0], c, 0, 0, 0);
            c = __builtin_amdgcn_mfma_f32_16x16x32_f16(a1, tb[qt][1], c, 0, 0, 0);
            int ql = qt * 16 + lq;
#pragma unroll
            for (int r = 0; r < 4; r += 2) {
                half2t h;
                h[0] = (_Float16)c[r];
                h[1] = (_Float16)c[r + 1];
                *(half2t*)&P[ql][pb + quad * 4 + r] = h;
            }
        }
    }
    __syncthreads();

    // --- softmax over p (rows = q) ---
    const int q  = tid & 31;
    const int ch = tid >> 5;   // 8 chunks of 128
    {
        float m = -1e30f;
#pragma unroll
        for (int i = 0; i < 16; ++i) {
            half8 v = *(const half8*)&P[q][ch * 128 + i * 8];
#pragma unroll
            for (int j = 0; j < 8; ++j) m = fmaxf(m, (float)v[j]);
        }
        red[ch][q] = m;
    }
    __syncthreads();
    if (tid < 32) {
        float m = red[0][tid];
#pragma unroll
        for (int j = 1; j < 8; ++j) m = fmaxf(m, red[j][tid]);
        m_s[tid] = m;
    }
    __syncthreads();
    {
        float m = m_s[q];
        float s = 0.f;
#pragma unroll
        for (int i = 0; i < 16; ++i) {
            half8 v = *(const half8*)&P[q][ch * 128 + i * 8];
            half8 o;
#pragma unroll
            for (int j = 0; j < 8; ++j) {
                float e = __expf((float)v[j] - m);
                s += e;
                o[j] = (_Float16)e;
            }
            *(half8*)&P[q][ch * 128 + i * 8] = o;
        }
        red[ch][q] = s;
    }
    __syncthreads();
    if (tid < 32) {
        float s = 0.f;
#pragma unroll
        for (int j = 0; j < 8; ++j) s += red[j][tid];
        inv_s[tid] = 1.0f / s;
    }
    __syncthreads();

    // --- PV phase: wave handles c in [wave*64, wave*64+64) ---
    f32x4 acc[4][2];
#pragma unroll
    for (int ct = 0; ct < 4; ++ct)
#pragma unroll
        for (int qt = 0; qt < 2; ++qt)
            acc[ct][qt] = (f32x4){0.f, 0.f, 0.f, 0.f};

    const _Float16* gN = g16 + (size_t)n * C2 * PP;
    const int cb = wave * 64;
    for (int kb = 0; kb < 32; ++kb) {
        half8 b0 = *(const half8*)&P[lq][kb * 32 + quad * 8];
        half8 b1 = *(const half8*)&P[16 + lq][kb * 32 + quad * 8];
#pragma unroll
        for (int ct = 0; ct < 4; ++ct) {
            half8 a = *(const half8*)&gN[(size_t)(cb + ct * 16 + lq) * PP + kb * 32 + quad * 8];
            acc[ct][0] = __builtin_amdgcn_mfma_f32_16x16x32_f16(a, b0, acc[ct][0], 0, 0, 0);
            acc[ct][1] = __builtin_amdgcn_mfma_f32_16x16x32_f16(a, b1, acc[ct][1], 0, 0, 0);
        }
    }

    // --- epilogue: O^T[c][q] * inv_l -> attn_out ---
    float i0 = inv_s[lq];
    float i1 = inv_s[16 + lq];
#pragma unroll
    for (int ct = 0; ct < 4; ++ct) {
#pragma unroll
        for (int qt = 0; qt < 2; ++qt) {
            float iv = qt ? i1 : i0;
            int qg = q0 + qt * 16 + lq;
#pragma unroll
            for (int r = 0; r < 4; ++r) {
                int c = cb + ct * 16 + quad * 4 + r;
                attn_out[((size_t)(n * C2 + c)) * HW + qg] = acc[ct][qt][r] * iv;
            }
        }
    }
}

// ---------------------------------------------------------------------------
extern "C" void kernel_launch(void* const* d_in, const int* in_sizes, int n_in,
                              void* d_out, int out_size, void* d_ws, size_t ws_size,
                              hipStream_t stream)
{
    const float* x       = (const float*)d_in[0];
    const float* theta_w = (const float*)d_in[1];
    const float* theta_b = (const float*)d_in[2];
    const float* phi_w   = (const float*)d_in[3];
    const float* phi_b   = (const float*)d_in[4];
    const float* g_w     = (const float*)d_in[5];
    const float* g_b     = (const float*)d_in[6];
    const float* out_w   = (const float*)d_in[7];
    const float* out_b   = (const float*)d_in[8];
    const float* gamma   = (const float*)d_in[9];
    float* out = (float*)d_out;

    float* ws = (float*)d_ws;
    _Float16* theta16 = (_Float16*)ws;                  // [8][4096][64]  = 2M halfs (1M floats)
    _Float16* phi16   = (_Float16*)(ws + 1048576);      // [8][1024][64]  = 512K halfs (256K floats)
    _Float16* g16     = (_Float16*)(ws + 1310720);      // [8][256][1024] = 2M halfs (1M floats)
    float*    D2      = ws + 2359296;                   // 8M floats scratch (32MB)

    // 1) theta = x . theta_w^T -> fp16 transposed [n][4096][64]
    gemm_k<512, 1><<<dim3(64, 1, NB), 256, 0, stream>>>(theta_w, theta_b, x, theta16, nullptr, nullptr);
    // 2) phi full fp32 -> D2
    gemm_k<512, 0><<<dim3(64, 1, NB), 256, 0, stream>>>(phi_w, phi_b, x, D2, nullptr, nullptr);
    // 3) pool+transpose phi -> phi16 [n][1024][64]
    pool_phi_t_k<<<dim3(256), 256, 0, stream>>>(D2, phi16);
    // 4) g full fp32 -> D2
    gemm_k<512, 0><<<dim3(64, 4, NB), 256, 0, stream>>>(g_w, g_b, x, D2, nullptr, nullptr);
    // 5) pool g -> g16 [n][256][1024]
    pool_g_h_k<<<dim3(8192), 256, 0, stream>>>(D2, g16);
    // 6) MFMA attention -> D2 (attn [8][256][4096] fp32)
    attn_mfma_k<<<dim3(128, NB), 256, 0, stream>>>(theta16, phi16, g16, D2);
    // 7) final conv + gamma*out + x -> d_out
    gemm_k<256, 2><<<dim3(64, 8, NB), 256, 0, stream>>>(out_w, out_b, D2, out, x, gamma);
}

// Round 3
// 298.656 us; speedup vs baseline: 4.2602x; 1.7529x over previous
//
#include <hip/hip_runtime.h>
#include <hip/hip_bf16.h>
#include <cmath>

#define NB 8
#define HW 4096
#define PP 1024
#define C2 256

typedef _Float16 half_t;
typedef _Float16 half8 __attribute__((ext_vector_type(8)));
typedef _Float16 half4 __attribute__((ext_vector_type(4)));
typedef _Float16 half2t __attribute__((ext_vector_type(2)));
typedef float f32x4 __attribute__((ext_vector_type(4)));

// ---------------------------------------------------------------------------
// Cast all weights fp32 -> fp16 into W16: [theta 64x512 | phi 64x512 |
// g 256x512 | out 512x256]  (total 327680 elems)
// ---------------------------------------------------------------------------
__global__ __launch_bounds__(256) void cast_w_k(
    const float* __restrict__ tw, const float* __restrict__ pw,
    const float* __restrict__ gw, const float* __restrict__ ow,
    half_t* __restrict__ W16)
{
    int gid = blockIdx.x * 256 + threadIdx.x;       // 40960 threads
    size_t i0 = (size_t)gid * 8;
    const float* src; size_t off;
    if (i0 < 32768)       { src = tw; off = i0; }
    else if (i0 < 65536)  { src = pw; off = i0 - 32768; }
    else if (i0 < 196608) { src = gw; off = i0 - 65536; }
    else                  { src = ow; off = i0 - 196608; }
    float4 a = *(const float4*)&src[off];
    float4 b = *(const float4*)&src[off + 4];
    half8 h;
    h[0] = (half_t)a.x; h[1] = (half_t)a.y; h[2] = (half_t)a.z; h[3] = (half_t)a.w;
    h[4] = (half_t)b.x; h[5] = (half_t)b.y; h[6] = (half_t)b.z; h[7] = (half_t)b.w;
    *(half8*)&W16[i0] = h;
}

// ---------------------------------------------------------------------------
// Cast+transpose x: [n][512 c][4096 p] fp32 -> x16t [n][4096 p][512 c] fp16
// block: 64c x 64p tile, LDS transpose
// ---------------------------------------------------------------------------
__global__ __launch_bounds__(256) void cast_xt_k(const float* __restrict__ x,
                                                 half_t* __restrict__ x16t)
{
    __shared__ half_t T[64][72];   // [p][c], stride 144 B
    const int tid = threadIdx.x;
    const int n = blockIdx.y;
    const int c0 = (blockIdx.x & 7) * 64;
    const int p0 = (blockIdx.x >> 3) * 64;

#pragma unroll
    for (int it = 0; it < 4; ++it) {
        int c = (tid >> 4) + 16 * it;
        int p4 = (tid & 15) * 4;
        float4 v = *(const float4*)&x[((size_t)n * 512 + c0 + c) * HW + p0 + p4];
        T[p4 + 0][c] = (half_t)v.x;
        T[p4 + 1][c] = (half_t)v.y;
        T[p4 + 2][c] = (half_t)v.z;
        T[p4 + 3][c] = (half_t)v.w;
    }
    __syncthreads();
#pragma unroll
    for (int it = 0; it < 2; ++it) {
        int p = (tid >> 3) + 32 * it;
        int ch = (tid & 7) * 8;
        half8 o = *(const half8*)&T[p][ch];
        *(half8*)&x16t[((size_t)n * HW + p0 + p) * 512 + c0 + ch] = o;
    }
}

// ---------------------------------------------------------------------------
// MFMA GEMM, 128x128 tile, BK=64, 4 waves (2x2), fp16 in, fp32 acc.
//   C[m][n] = sum_c A[m][c] * B[n][c]^T   (B16 is [row n][col c], c contig)
// MODE 0: theta+phi fused (m0=0): waves wm=0 -> theta transposed fp16 out;
//         wm=64 -> phi, pooled 2x2 + transposed fp16 out.
// MODE 1: g projection, pooled 2x2 epilogue -> [n][C2][PP] fp16.
// MODE 2: final conv: fp32 out = gamma*(acc+bias) + resid.
// ---------------------------------------------------------------------------
template<int MODE, int CIN>
__global__ __launch_bounds__(256, 2) void mfma_gemm(
    const half_t* __restrict__ A16, const float* __restrict__ bias_a,
    const float* __restrict__ bias_b, const half_t* __restrict__ B16,
    half_t* __restrict__ outA, half_t* __restrict__ outB,
    float* __restrict__ outF, const float* __restrict__ resid,
    const float* __restrict__ gam)
{
    __shared__ __align__(16) char smem[36864];
    half_t* As = (half_t*)smem;              // [128][72]
    half_t* Bs = (half_t*)(smem + 18432);    // [128][72]

    const int tid = threadIdx.x;
    const int wave = tid >> 6, lane = tid & 63;
    const int quad = lane >> 4, lq = lane & 15;
    const int wn = (wave & 1) * 64, wm = (wave >> 1) * 64;
    const int n = blockIdx.z;
    const int p0 = blockIdx.x * 128;
    const int m0 = blockIdx.y * 128;

    const int srow = tid >> 3;
    const int schunk = (tid & 7) * 8;

    f32x4 acc[4][4];
#pragma unroll
    for (int mt = 0; mt < 4; ++mt)
#pragma unroll
        for (int nt = 0; nt < 4; ++nt)
            acc[mt][nt] = (f32x4){0.f, 0.f, 0.f, 0.f};

    for (int c0 = 0; c0 < CIN; c0 += 64) {
#pragma unroll
        for (int i = 0; i < 4; ++i) {
            int r = srow + 32 * i;
            *(half8*)&As[r * 72 + schunk] =
                *(const half8*)&A16[(size_t)(m0 + r) * CIN + c0 + schunk];
        }
#pragma unroll
        for (int i = 0; i < 4; ++i) {
            int r = srow + 32 * i;
            *(half8*)&Bs[r * 72 + schunk] =
                *(const half8*)&B16[((size_t)n * HW + p0 + r) * CIN + c0 + schunk];
        }
        __syncthreads();
#pragma unroll
        for (int ks = 0; ks < 2; ++ks) {
            half8 af[4], bf[4];
#pragma unroll
            for (int mt = 0; mt < 4; ++mt)
                af[mt] = *(const half8*)&As[(wm + mt * 16 + lq) * 72 + ks * 32 + quad * 8];
#pragma unroll
            for (int nt = 0; nt < 4; ++nt)
                bf[nt] = *(const half8*)&Bs[(wn + nt * 16 + lq) * 72 + ks * 32 + quad * 8];
#pragma unroll
            for (int mt = 0; mt < 4; ++mt)
#pragma unroll
                for (int nt = 0; nt < 4; ++nt)
                    acc[mt][nt] = __builtin_amdgcn_mfma_f32_16x16x32_f16(
                        af[mt], bf[nt], acc[mt][nt], 0, 0, 0);
        }
        __syncthreads();
    }

    if (MODE == 0) {
        half_t* Cs = (half_t*)smem;   // [64][136] phi C-tile
        if (wm == 0) {
            // theta: transposed write [n][q][64]
#pragma unroll
            for (int mt = 0; mt < 4; ++mt) {
                float4 bv = *(const float4*)&bias_a[mt * 16 + quad * 4];
#pragma unroll
                for (int nt = 0; nt < 4; ++nt) {
                    int q = p0 + wn + nt * 16 + lq;
                    half4 h;
                    h[0] = (half_t)(acc[mt][nt][0] + bv.x);
                    h[1] = (half_t)(acc[mt][nt][1] + bv.y);
                    h[2] = (half_t)(acc[mt][nt][2] + bv.z);
                    h[3] = (half_t)(acc[mt][nt][3] + bv.w);
                    *(half4*)&outA[((size_t)n * HW + q) * 64 + mt * 16 + quad * 4] = h;
                }
            }
        } else {
            // phi: stage C (with bias) to LDS
#pragma unroll
            for (int mt = 0; mt < 4; ++mt) {
                float4 bv = *(const float4*)&bias_b[mt * 16 + quad * 4];
#pragma unroll
                for (int nt = 0; nt < 4; ++nt) {
                    int col = wn + nt * 16 + lq;
                    int mr = mt * 16 + quad * 4;
                    Cs[(mr + 0) * 136 + col] = (half_t)(acc[mt][nt][0] + bv.x);
                    Cs[(mr + 1) * 136 + col] = (half_t)(acc[mt][nt][1] + bv.y);
                    Cs[(mr + 2) * 136 + col] = (half_t)(acc[mt][nt][2] + bv.z);
                    Cs[(mr + 3) * 136 + col] = (half_t)(acc[mt][nt][3] + bv.w);
                }
            }
        }
        __syncthreads();
        // pooled (2x2 over the 128-col = rows h,h+1) transposed phi write
        {
            int pw = tid >> 3;
            int kc = (tid & 7) * 8;
            half8 o;
#pragma unroll
            for (int jj = 0; jj < 8; ++jj) {
                int k = kc + jj;
                float v0 = (float)Cs[k * 136 + 2 * pw];
                float v1 = (float)Cs[k * 136 + 2 * pw + 1];
                float v2 = (float)Cs[k * 136 + 64 + 2 * pw];
                float v3 = (float)Cs[k * 136 + 65 + 2 * pw];
                o[jj] = (half_t)fmaxf(fmaxf(v0, v1), fmaxf(v2, v3));
            }
            *(half8*)&outB[((size_t)n * PP + (p0 >> 7) * 32 + pw) * 64 + kc] = o;
        }
    } else if (MODE == 1) {
        half_t* Cs = (half_t*)smem;   // [128][136] = 34816 B
#pragma unroll
        for (int mt = 0; mt < 4; ++mt) {
            float4 bv = *(const float4*)&bias_a[m0 + wm + mt * 16 + quad * 4];
#pragma unroll
            for (int nt = 0; nt < 4; ++nt) {
                int col = wn + nt * 16 + lq;
                int mr = wm + mt * 16 + quad * 4;
                Cs[(mr + 0) * 136 + col] = (half_t)(acc[mt][nt][0] + bv.x);
                Cs[(mr + 1) * 136 + col] = (half_t)(acc[mt][nt][1] + bv.y);
                Cs[(mr + 2) * 136 + col] = (half_t)(acc[mt][nt][2] + bv.z);
                Cs[(mr + 3) * 136 + col] = (half_t)(acc[mt][nt][3] + bv.w);
            }
        }
        __syncthreads();
#pragma unroll
        for (int i = 0; i < 16; ++i) {
            int m = (tid >> 5) + 8 * i;
            int pw = tid & 31;
            float v0 = (float)Cs[m * 136 + 2 * pw];
            float v1 = (float)Cs[m * 136 + 2 * pw + 1];
            float v2 = (float)Cs[m * 136 + 64 + 2 * pw];
            float v3 = (float)Cs[m * 136 + 65 + 2 * pw];
            outB[((size_t)n * C2 + m0 + m) * PP + (p0 >> 7) * 32 + pw] =
                (half_t)fmaxf(fmaxf(v0, v1), fmaxf(v2, v3));
        }
    } else {
        float g0 = gam[0];
#pragma unroll
        for (int mt = 0; mt < 4; ++mt) {
            float4 bv = *(const float4*)&bias_a[m0 + wm + mt * 16 + quad * 4];
#pragma unroll
            for (int nt = 0; nt < 4; ++nt) {
                int q = p0 + wn + nt * 16 + lq;
                int m = m0 + wm + mt * 16 + quad * 4;
                size_t off0 = ((size_t)n * 512 + m) * HW + q;
                outF[off0]            = g0 * (acc[mt][nt][0] + bv.x) + resid[off0];
                outF[off0 + HW]       = g0 * (acc[mt][nt][1] + bv.y) + resid[off0 + HW];
                outF[off0 + 2 * HW]   = g0 * (acc[mt][nt][2] + bv.z) + resid[off0 + 2 * HW];
                outF[off0 + 3 * HW]   = g0 * (acc[mt][nt][3] + bv.w) + resid[off0 + 3 * HW];
            }
        }
    }
}

// ---------------------------------------------------------------------------
// MFMA attention (as R2) but epilogue writes attn_t fp16 [n][4096 q][256 c]
// ---------------------------------------------------------------------------
__global__ __launch_bounds__(256, 2) void attn_mfma_k(
    const half_t* __restrict__ theta16,   // [n][4096][64]
    const half_t* __restrict__ phi16,     // [n][1024][64]
    const half_t* __restrict__ g16,       // [n][256][1024]
    half_t* __restrict__ attn_t)          // [n][4096][256]
{
    __shared__ half_t P[32][1032];
    __shared__ float red[8][32];
    __shared__ float m_s[32];
    __shared__ float inv_s[32];

    const int tid  = threadIdx.x;
    const int wave = tid >> 6;
    const int lane = tid & 63;
    const int quad = lane >> 4;
    const int lq   = lane & 15;
    const int n  = blockIdx.y;
    const int q0 = blockIdx.x * 32;

    half8 tb[2][2];
#pragma unroll
    for (int qt = 0; qt < 2; ++qt)
#pragma unroll
        for (int kb = 0; kb < 2; ++kb)
            tb[qt][kb] = *(const half8*)&theta16[((size_t)(n * HW) + q0 + qt * 16 + lq) * 64 + kb * 32 + quad * 8];

    const half_t* phiN = phi16 + (size_t)n * PP * 64;
#pragma unroll 4
    for (int pt = 0; pt < 16; ++pt) {
        int pb = wave * 256 + pt * 16;
        half8 a0 = *(const half8*)&phiN[(size_t)(pb + lq) * 64 + quad * 8];
        half8 a1 = *(const half8*)&phiN[(size_t)(pb + lq) * 64 + 32 + quad * 8];
#pragma unroll
        for (int qt = 0; qt < 2; ++qt) {
            f32x4 c = {0.f, 0.f, 0.f, 0.f};
            c = __builtin_amdgcn_mfma_f32_16x16x32_f16(a0, tb[qt][0], c, 0, 0, 0);
            c = __builtin_amdgcn_mfma_f32_16x16x32_f16(a1, tb[qt][1], c, 0, 0, 0);
            int ql = qt * 16 + lq;
#pragma unroll
            for (int r = 0; r < 4; r += 2) {
                half2t h;
                h[0] = (half_t)c[r];
                h[1] = (half_t)c[r + 1];
                *(half2t*)&P[ql][pb + quad * 4 + r] = h;
            }
        }
    }
    __syncthreads();

    const int q  = tid & 31;
    const int ch = tid >> 5;
    {
        float m = -1e30f;
#pragma unroll
        for (int i = 0; i < 16; ++i) {
            half8 v = *(const half8*)&P[q][ch * 128 + i * 8];
#pragma unroll
            for (int j = 0; j < 8; ++j) m = fmaxf(m, (float)v[j]);
        }
        red[ch][q] = m;
    }
    __syncthreads();
    if (tid < 32) {
        float m = red[0][tid];
#pragma unroll
        for (int j = 1; j < 8; ++j) m = fmaxf(m, red[j][tid]);
        m_s[tid] = m;
    }
    __syncthreads();
    {
        float m = m_s[q];
        float s = 0.f;
#pragma unroll
        for (int i = 0; i < 16; ++i) {
            half8 v = *(const half8*)&P[q][ch * 128 + i * 8];
            half8 o;
#pragma unroll
            for (int j = 0; j < 8; ++j) {
                float e = __expf((float)v[j] - m);
                s += e;
                o[j] = (half_t)e;
            }
            *(half8*)&P[q][ch * 128 + i * 8] = o;
        }
        red[ch][q] = s;
    }
    __syncthreads();
    if (tid < 32) {
        float s = 0.f;
#pragma unroll
        for (int j = 0; j < 8; ++j) s += red[j][tid];
        inv_s[tid] = 1.0f / s;
    }
    __syncthreads();

    f32x4 acc[4][2];
#pragma unroll
    for (int ct = 0; ct < 4; ++ct)
#pragma unroll
        for (int qt = 0; qt < 2; ++qt)
            acc[ct][qt] = (f32x4){0.f, 0.f, 0.f, 0.f};

    const half_t* gN = g16 + (size_t)n * C2 * PP;
    const int cb = wave * 64;
    for (int kb = 0; kb < 32; ++kb) {
        half8 b0 = *(const half8*)&P[lq][kb * 32 + quad * 8];
        half8 b1 = *(const half8*)&P[16 + lq][kb * 32 + quad * 8];
#pragma unroll
        for (int ct = 0; ct < 4; ++ct) {
            half8 a = *(const half8*)&gN[(size_t)(cb + ct * 16 + lq) * PP + kb * 32 + quad * 8];
            acc[ct][0] = __builtin_amdgcn_mfma_f32_16x16x32_f16(a, b0, acc[ct][0], 0, 0, 0);
            acc[ct][1] = __builtin_amdgcn_mfma_f32_16x16x32_f16(a, b1, acc[ct][1], 0, 0, 0);
        }
    }

    float i0 = inv_s[lq];
    float i1 = inv_s[16 + lq];
#pragma unroll
    for (int ct = 0; ct < 4; ++ct) {
#pragma unroll
        for (int qt = 0; qt < 2; ++qt) {
            float iv = qt ? i1 : i0;
            int qg = q0 + qt * 16 + lq;
            half4 h;
#pragma unroll
            for (int r = 0; r < 4; ++r) h[r] = (half_t)(acc[ct][qt][r] * iv);
            *(half4*)&attn_t[((size_t)n * HW + qg) * C2 + cb + ct * 16 + quad * 4] = h;
        }
    }
}

// ---------------------------------------------------------------------------
extern "C" void kernel_launch(void* const* d_in, const int* in_sizes, int n_in,
                              void* d_out, int out_size, void* d_ws, size_t ws_size,
                              hipStream_t stream)
{
    const float* x       = (const float*)d_in[0];
    const float* theta_w = (const float*)d_in[1];
    const float* theta_b = (const float*)d_in[2];
    const float* phi_w   = (const float*)d_in[3];
    const float* phi_b   = (const float*)d_in[4];
    const float* g_w     = (const float*)d_in[5];
    const float* g_b     = (const float*)d_in[6];
    const float* out_w   = (const float*)d_in[7];
    const float* out_b   = (const float*)d_in[8];
    const float* gamma   = (const float*)d_in[9];
    float* out = (float*)d_out;

    char* wsb = (char*)d_ws;
    half_t* x16t    = (half_t*)wsb;                    // 33,554,432 B
    half_t* attn_t  = (half_t*)wsb;                    // overlays x16t (dead by then)
    half_t* W16     = (half_t*)(wsb + 33554432);       // 655,360 B
    half_t* theta16 = (half_t*)(wsb + 34209792);       // 4,194,304 B
    half_t* phi16   = (half_t*)(wsb + 38404096);       // 1,048,576 B
    half_t* g16     = (half_t*)(wsb + 39452672);       // 4,194,304 B

    // 1) weights -> fp16
    cast_w_k<<<160, 256, 0, stream>>>(theta_w, phi_w, g_w, out_w, W16);
    // 2) x -> x16t [n][p][c] fp16
    cast_xt_k<<<dim3(512, NB), 256, 0, stream>>>(x, x16t);
    // 3) theta + phi fused projection (theta transposed; phi pooled+transposed)
    mfma_gemm<0, 512><<<dim3(32, 1, NB), 256, 0, stream>>>(
        W16, theta_b, phi_b, x16t, theta16, phi16, nullptr, nullptr, nullptr);
    // 4) g projection, pooled epilogue
    mfma_gemm<1, 512><<<dim3(32, 2, NB), 256, 0, stream>>>(
        W16 + 65536, g_b, nullptr, x16t, nullptr, g16, nullptr, nullptr, nullptr);
    // 5) attention -> attn_t fp16 [n][q][256]
    attn_mfma_k<<<dim3(128, NB), 256, 0, stream>>>(theta16, phi16, g16, attn_t);
    // 6) final conv + gamma + residual -> out
    mfma_gemm<2, 256><<<dim3(32, 4, NB), 256, 0, stream>>>(
        W16 + 196608, out_b, nullptr, attn_t, nullptr, nullptr, out, x, gamma);
}

// Round 4
// 271.516 us; speedup vs baseline: 4.6861x; 1.1000x over previous
//
#include <hip/hip_runtime.h>
#include <hip/hip_bf16.h>
#include <cmath>

#define NB 8
#define HW 4096
#define PP 1024
#define C2 256

typedef _Float16 half_t;
typedef _Float16 half8 __attribute__((ext_vector_type(8)));
typedef _Float16 half4 __attribute__((ext_vector_type(4)));
typedef _Float16 half2t __attribute__((ext_vector_type(2)));
typedef float f32x4 __attribute__((ext_vector_type(4)));

// ---------------------------------------------------------------------------
// Cast all weights fp32 -> fp16 into W16: [theta 64x512 | phi 64x512 |
// g 256x512 | out 512x256]  (total 327680 elems)
// ---------------------------------------------------------------------------
__global__ __launch_bounds__(256) void cast_w_k(
    const float* __restrict__ tw, const float* __restrict__ pw,
    const float* __restrict__ gw, const float* __restrict__ ow,
    half_t* __restrict__ W16)
{
    int gid = blockIdx.x * 256 + threadIdx.x;       // 40960 threads
    size_t i0 = (size_t)gid * 8;
    const float* src; size_t off;
    if (i0 < 32768)       { src = tw; off = i0; }
    else if (i0 < 65536)  { src = pw; off = i0 - 32768; }
    else if (i0 < 196608) { src = gw; off = i0 - 65536; }
    else                  { src = ow; off = i0 - 196608; }
    float4 a = *(const float4*)&src[off];
    float4 b = *(const float4*)&src[off + 4];
    half8 h;
    h[0] = (half_t)a.x; h[1] = (half_t)a.y; h[2] = (half_t)a.z; h[3] = (half_t)a.w;
    h[4] = (half_t)b.x; h[5] = (half_t)b.y; h[6] = (half_t)b.z; h[7] = (half_t)b.w;
    *(half8*)&W16[i0] = h;
}

// ---------------------------------------------------------------------------
// Cast+transpose x: [n][512 c][4096 p] fp32 -> x16t [n][4096 p][512 c] fp16
// ---------------------------------------------------------------------------
__global__ __launch_bounds__(256) void cast_xt_k(const float* __restrict__ x,
                                                 half_t* __restrict__ x16t)
{
    __shared__ half_t T[64][72];
    const int tid = threadIdx.x;
    const int n = blockIdx.y;
    const int c0 = (blockIdx.x & 7) * 64;
    const int p0 = (blockIdx.x >> 3) * 64;

#pragma unroll
    for (int it = 0; it < 4; ++it) {
        int c = (tid >> 4) + 16 * it;
        int p4 = (tid & 15) * 4;
        float4 v = *(const float4*)&x[((size_t)n * 512 + c0 + c) * HW + p0 + p4];
        T[p4 + 0][c] = (half_t)v.x;
        T[p4 + 1][c] = (half_t)v.y;
        T[p4 + 2][c] = (half_t)v.z;
        T[p4 + 3][c] = (half_t)v.w;
    }
    __syncthreads();
#pragma unroll
    for (int it = 0; it < 2; ++it) {
        int p = (tid >> 3) + 32 * it;
        int ch = (tid & 7) * 8;
        half8 o = *(const half8*)&T[p][ch];
        *(half8*)&x16t[((size_t)n * HW + p0 + p) * 512 + c0 + ch] = o;
    }
}

// ---------------------------------------------------------------------------
// Fused projection GEMM, 128x128 tile, BK=64, 4 waves.
// blockIdx.y == 0: A = [theta(64) | phi(64)] rows; epilogue: theta transposed
//   fp16 out + phi pooled 2x2 + transposed fp16 out.
// blockIdx.y == 1,2: A = g rows (y-1)*128..; epilogue: pooled 2x2 -> g16.
// ---------------------------------------------------------------------------
__global__ __launch_bounds__(256, 2) void proj_k(
    const half_t* __restrict__ W16, const float* __restrict__ theta_b,
    const float* __restrict__ phi_b, const float* __restrict__ g_b,
    const half_t* __restrict__ x16t, half_t* __restrict__ theta16,
    half_t* __restrict__ phi16, half_t* __restrict__ g16)
{
    __shared__ __align__(16) char smem[36864];
    half_t* As = (half_t*)smem;              // [128][72]
    half_t* Bs = (half_t*)(smem + 18432);    // [128][72]

    const int tid = threadIdx.x;
    const int wave = tid >> 6, lane = tid & 63;
    const int quad = lane >> 4, lq = lane & 15;
    const int wn = (wave & 1) * 64, wm = (wave >> 1) * 64;
    const int n = blockIdx.z;
    const int p0 = blockIdx.x * 128;
    const int ysel = blockIdx.y;

    const half_t* A16 = (ysel == 0) ? W16
                        : (W16 + 65536 + (size_t)(ysel - 1) * 128 * 512);

    const int srow = tid >> 3;
    const int schunk = (tid & 7) * 8;

    f32x4 acc[4][4];
#pragma unroll
    for (int mt = 0; mt < 4; ++mt)
#pragma unroll
        for (int nt = 0; nt < 4; ++nt)
            acc[mt][nt] = (f32x4){0.f, 0.f, 0.f, 0.f};

    for (int c0 = 0; c0 < 512; c0 += 64) {
#pragma unroll
        for (int i = 0; i < 4; ++i) {
            int r = srow + 32 * i;
            *(half8*)&As[r * 72 + schunk] =
                *(const half8*)&A16[(size_t)r * 512 + c0 + schunk];
        }
#pragma unroll
        for (int i = 0; i < 4; ++i) {
            int r = srow + 32 * i;
            *(half8*)&Bs[r * 72 + schunk] =
                *(const half8*)&x16t[((size_t)n * HW + p0 + r) * 512 + c0 + schunk];
        }
        __syncthreads();
#pragma unroll
        for (int ks = 0; ks < 2; ++ks) {
            half8 af[4], bf[4];
#pragma unroll
            for (int mt = 0; mt < 4; ++mt)
                af[mt] = *(const half8*)&As[(wm + mt * 16 + lq) * 72 + ks * 32 + quad * 8];
#pragma unroll
            for (int nt = 0; nt < 4; ++nt)
                bf[nt] = *(const half8*)&Bs[(wn + nt * 16 + lq) * 72 + ks * 32 + quad * 8];
#pragma unroll
            for (int mt = 0; mt < 4; ++mt)
#pragma unroll
                for (int nt = 0; nt < 4; ++nt)
                    acc[mt][nt] = __builtin_amdgcn_mfma_f32_16x16x32_f16(
                        af[mt], bf[nt], acc[mt][nt], 0, 0, 0);
        }
        __syncthreads();
    }

    if (ysel == 0) {
        half_t* Cs = (half_t*)smem;   // [64][136] phi C-tile
        if (wm == 0) {
            // theta rows 0..63: transposed write [n][q][64]
#pragma unroll
            for (int mt = 0; mt < 4; ++mt) {
                float4 bv = *(const float4*)&theta_b[mt * 16 + quad * 4];
#pragma unroll
                for (int nt = 0; nt < 4; ++nt) {
                    int q = p0 + wn + nt * 16 + lq;
                    half4 h;
                    h[0] = (half_t)(acc[mt][nt][0] + bv.x);
                    h[1] = (half_t)(acc[mt][nt][1] + bv.y);
                    h[2] = (half_t)(acc[mt][nt][2] + bv.z);
                    h[3] = (half_t)(acc[mt][nt][3] + bv.w);
                    *(half4*)&theta16[((size_t)n * HW + q) * 64 + mt * 16 + quad * 4] = h;
                }
            }
        } else {
            // phi rows 64..127: stage C (with bias) to LDS
#pragma unroll
            for (int mt = 0; mt < 4; ++mt) {
                float4 bv = *(const float4*)&phi_b[mt * 16 + quad * 4];
#pragma unroll
                for (int nt = 0; nt < 4; ++nt) {
                    int col = wn + nt * 16 + lq;
                    int mr = mt * 16 + quad * 4;
                    Cs[(mr + 0) * 136 + col] = (half_t)(acc[mt][nt][0] + bv.x);
                    Cs[(mr + 1) * 136 + col] = (half_t)(acc[mt][nt][1] + bv.y);
                    Cs[(mr + 2) * 136 + col] = (half_t)(acc[mt][nt][2] + bv.z);
                    Cs[(mr + 3) * 136 + col] = (half_t)(acc[mt][nt][3] + bv.w);
                }
            }
        }
        __syncthreads();
        {
            int pw = tid >> 3;
            int kc = (tid & 7) * 8;
            half8 o;
#pragma unroll
            for (int jj = 0; jj < 8; ++jj) {
                int k = kc + jj;
                float v0 = (float)Cs[k * 136 + 2 * pw];
                float v1 = (float)Cs[k * 136 + 2 * pw + 1];
                float v2 = (float)Cs[k * 136 + 64 + 2 * pw];
                float v3 = (float)Cs[k * 136 + 65 + 2 * pw];
                o[jj] = (half_t)fmaxf(fmaxf(v0, v1), fmaxf(v2, v3));
            }
            *(half8*)&phi16[((size_t)n * PP + (p0 >> 7) * 32 + pw) * 64 + kc] = o;
        }
    } else {
        const int m0 = (ysel - 1) * 128;
        half_t* Cs = (half_t*)smem;   // [128][136] = 34816 B
#pragma unroll
        for (int mt = 0; mt < 4; ++mt) {
            float4 bv = *(const float4*)&g_b[m0 + wm + mt * 16 + quad * 4];
#pragma unroll
            for (int nt = 0; nt < 4; ++nt) {
                int col = wn + nt * 16 + lq;
                int mr = wm + mt * 16 + quad * 4;
                Cs[(mr + 0) * 136 + col] = (half_t)(acc[mt][nt][0] + bv.x);
                Cs[(mr + 1) * 136 + col] = (half_t)(acc[mt][nt][1] + bv.y);
                Cs[(mr + 2) * 136 + col] = (half_t)(acc[mt][nt][2] + bv.z);
                Cs[(mr + 3) * 136 + col] = (half_t)(acc[mt][nt][3] + bv.w);
            }
        }
        __syncthreads();
#pragma unroll
        for (int i = 0; i < 16; ++i) {
            int m = (tid >> 5) + 8 * i;
            int pw = tid & 31;
            float v0 = (float)Cs[m * 136 + 2 * pw];
            float v1 = (float)Cs[m * 136 + 2 * pw + 1];
            float v2 = (float)Cs[m * 136 + 64 + 2 * pw];
            float v3 = (float)Cs[m * 136 + 65 + 2 * pw];
            g16[((size_t)n * C2 + m0 + m) * PP + (p0 >> 7) * 32 + pw] =
                (half_t)fmaxf(fmaxf(v0, v1), fmaxf(v2, v3));
        }
    }
}

// ---------------------------------------------------------------------------
// Final conv GEMM (K=256): fp32 out = gamma*(acc+bias) + resid
// ---------------------------------------------------------------------------
__global__ __launch_bounds__(256, 2) void final_k(
    const half_t* __restrict__ A16, const float* __restrict__ bias,
    const half_t* __restrict__ B16, float* __restrict__ outF,
    const float* __restrict__ resid, const float* __restrict__ gam)
{
    __shared__ __align__(16) char smem[36864];
    half_t* As = (half_t*)smem;
    half_t* Bs = (half_t*)(smem + 18432);

    const int tid = threadIdx.x;
    const int wave = tid >> 6, lane = tid & 63;
    const int quad = lane >> 4, lq = lane & 15;
    const int wn = (wave & 1) * 64, wm = (wave >> 1) * 64;
    const int n = blockIdx.z;
    const int p0 = blockIdx.x * 128;
    const int m0 = blockIdx.y * 128;

    const int srow = tid >> 3;
    const int schunk = (tid & 7) * 8;

    f32x4 acc[4][4];
#pragma unroll
    for (int mt = 0; mt < 4; ++mt)
#pragma unroll
        for (int nt = 0; nt < 4; ++nt)
            acc[mt][nt] = (f32x4){0.f, 0.f, 0.f, 0.f};

    for (int c0 = 0; c0 < 256; c0 += 64) {
#pragma unroll
        for (int i = 0; i < 4; ++i) {
            int r = srow + 32 * i;
            *(half8*)&As[r * 72 + schunk] =
                *(const half8*)&A16[(size_t)(m0 + r) * 256 + c0 + schunk];
        }
#pragma unroll
        for (int i = 0; i < 4; ++i) {
            int r = srow + 32 * i;
            *(half8*)&Bs[r * 72 + schunk] =
                *(const half8*)&B16[((size_t)n * HW + p0 + r) * 256 + c0 + schunk];
        }
        __syncthreads();
#pragma unroll
        for (int ks = 0; ks < 2; ++ks) {
            half8 af[4], bf[4];
#pragma unroll
            for (int mt = 0; mt < 4; ++mt)
                af[mt] = *(const half8*)&As[(wm + mt * 16 + lq) * 72 + ks * 32 + quad * 8];
#pragma unroll
            for (int nt = 0; nt < 4; ++nt)
                bf[nt] = *(const half8*)&Bs[(wn + nt * 16 + lq) * 72 + ks * 32 + quad * 8];
#pragma unroll
            for (int mt = 0; mt < 4; ++mt)
#pragma unroll
                for (int nt = 0; nt < 4; ++nt)
                    acc[mt][nt] = __builtin_amdgcn_mfma_f32_16x16x32_f16(
                        af[mt], bf[nt], acc[mt][nt], 0, 0, 0);
        }
        __syncthreads();
    }

    float g0 = gam[0];
#pragma unroll
    for (int mt = 0; mt < 4; ++mt) {
        float4 bv = *(const float4*)&bias[m0 + wm + mt * 16 + quad * 4];
#pragma unroll
        for (int nt = 0; nt < 4; ++nt) {
            int q = p0 + wn + nt * 16 + lq;
            int m = m0 + wm + mt * 16 + quad * 4;
            size_t off0 = ((size_t)n * 512 + m) * HW + q;
            outF[off0]          = g0 * (acc[mt][nt][0] + bv.x) + resid[off0];
            outF[off0 + HW]     = g0 * (acc[mt][nt][1] + bv.y) + resid[off0 + HW];
            outF[off0 + 2 * HW] = g0 * (acc[mt][nt][2] + bv.z) + resid[off0 + 2 * HW];
            outF[off0 + 3 * HW] = g0 * (acc[mt][nt][3] + bv.w) + resid[off0 + 3 * HW];
        }
    }
}

// ---------------------------------------------------------------------------
// Flash MFMA attention: block = (n, 32 q), 4 waves, 2 chunks of 512 p with
// online softmax. LDS ~36.9 KB -> 4 blocks/CU.
// ---------------------------------------------------------------------------
__global__ __launch_bounds__(256, 4) void attn_flash_k(
    const half_t* __restrict__ theta16,   // [n][4096][64]
    const half_t* __restrict__ phi16,     // [n][1024][64]
    const half_t* __restrict__ g16,       // [n][256][1024]
    half_t* __restrict__ attn_t)          // [n][4096][256]
{
    __shared__ half_t P[32][520];          // 33280 B
    __shared__ float redM[16][32];         // 2048 B
    __shared__ float redS[8][32];          // 1024 B
    __shared__ float Ms[32], alpha_s[32], l_s[32], inv_s[32];

    const int tid  = threadIdx.x;
    const int wave = tid >> 6;
    const int lane = tid & 63;
    const int quad = lane >> 4;
    const int lq   = lane & 15;
    const int n  = blockIdx.y;
    const int q0 = blockIdx.x * 32;

    // theta B-fragments, held for the whole kernel
    half8 tb[2][2];
#pragma unroll
    for (int qt = 0; qt < 2; ++qt)
#pragma unroll
        for (int kb = 0; kb < 2; ++kb)
            tb[qt][kb] = *(const half8*)&theta16[((size_t)(n * HW) + q0 + qt * 16 + lq) * 64 + kb * 32 + quad * 8];

    f32x4 acc[4][2];
#pragma unroll
    for (int ct = 0; ct < 4; ++ct)
#pragma unroll
        for (int qt = 0; qt < 2; ++qt)
            acc[ct][qt] = (f32x4){0.f, 0.f, 0.f, 0.f};

    if (tid < 32) { Ms[tid] = -1e30f; l_s[tid] = 0.f; }

    const half_t* phiN = phi16 + (size_t)n * PP * 64;
    const half_t* gN   = g16 + (size_t)n * C2 * PP;
    const int cb = wave * 64;

    for (int chunk = 0; chunk < 2; ++chunk) {
        // --- E phase: wave covers 128 p of this 512-chunk; track reg max ---
        float mreg0 = -1e30f, mreg1 = -1e30f;
#pragma unroll
        for (int pt = 0; pt < 8; ++pt) {
            int pl = wave * 128 + pt * 16;            // chunk-local p base
            int pg = chunk * 512 + pl;                // global p
            half8 a0 = *(const half8*)&phiN[(size_t)(pg + lq) * 64 + quad * 8];
            half8 a1 = *(const half8*)&phiN[(size_t)(pg + lq) * 64 + 32 + quad * 8];
#pragma unroll
            for (int qt = 0; qt < 2; ++qt) {
                f32x4 c = {0.f, 0.f, 0.f, 0.f};
                c = __builtin_amdgcn_mfma_f32_16x16x32_f16(a0, tb[qt][0], c, 0, 0, 0);
                c = __builtin_amdgcn_mfma_f32_16x16x32_f16(a1, tb[qt][1], c, 0, 0, 0);
                float mlocal = fmaxf(fmaxf(c[0], c[1]), fmaxf(c[2], c[3]));
                if (qt == 0) mreg0 = fmaxf(mreg0, mlocal);
                else         mreg1 = fmaxf(mreg1, mlocal);
                int ql = qt * 16 + lq;
                int pb = pl + quad * 4;
                half2t h0; h0[0] = (half_t)c[0]; h0[1] = (half_t)c[1];
                half2t h1; h1[0] = (half_t)c[2]; h1[1] = (half_t)c[3];
                *(half2t*)&P[ql][pb]     = h0;
                *(half2t*)&P[ql][pb + 2] = h1;
            }
        }
        redM[wave * 4 + quad][lq]      = mreg0;
        redM[wave * 4 + quad][16 + lq] = mreg1;
        __syncthreads();                               // B1

        // --- finalize running max + alpha (one wave slice) ---
        if (tid < 32) {
            float cm = redM[0][tid];
#pragma unroll
            for (int j = 1; j < 16; ++j) cm = fmaxf(cm, redM[j][tid]);
            float Mo = Ms[tid];
            float Mn = fmaxf(Mo, cm);
            alpha_s[tid] = __expf(Mo - Mn);
            Ms[tid] = Mn;
        }
        __syncthreads();                               // B2

        // --- rescale O accumulators ---
        {
            float al0 = alpha_s[lq], al1 = alpha_s[16 + lq];
#pragma unroll
            for (int ct = 0; ct < 4; ++ct) {
#pragma unroll
                for (int r = 0; r < 4; ++r) {
                    acc[ct][0][r] *= al0;
                    acc[ct][1][r] *= al1;
                }
            }
        }

        // --- exp pass + per-q partial sums ---
        {
            int q = tid & 31, ch = tid >> 5;
            float Mn = Ms[q];
            float s = 0.f;
#pragma unroll
            for (int i = 0; i < 8; ++i) {
                half8 v = *(const half8*)&P[q][ch * 64 + i * 8];
                half8 o;
#pragma unroll
                for (int j = 0; j < 8; ++j) {
                    float e = __expf((float)v[j] - Mn);
                    s += e;
                    o[j] = (half_t)e;
                }
                *(half8*)&P[q][ch * 64 + i * 8] = o;
            }
            redS[ch][q] = s;
        }
        __syncthreads();                               // B3

        if (tid < 32) {
            float s = 0.f;
#pragma unroll
            for (int j = 0; j < 8; ++j) s += redS[j][tid];
            l_s[tid] = l_s[tid] * alpha_s[tid] + s;
        }

        // --- PV phase: wave covers 64 c; k over this chunk's 512 p ---
#pragma unroll 4
        for (int kb = 0; kb < 16; ++kb) {
            half8 b0 = *(const half8*)&P[lq][kb * 32 + quad * 8];
            half8 b1 = *(const half8*)&P[16 + lq][kb * 32 + quad * 8];
            int kg = chunk * 512 + kb * 32 + quad * 8;
#pragma unroll
            for (int ct = 0; ct < 4; ++ct) {
                half8 a = *(const half8*)&gN[(size_t)(cb + ct * 16 + lq) * PP + kg];
                acc[ct][0] = __builtin_amdgcn_mfma_f32_16x16x32_f16(a, b0, acc[ct][0], 0, 0, 0);
                acc[ct][1] = __builtin_amdgcn_mfma_f32_16x16x32_f16(a, b1, acc[ct][1], 0, 0, 0);
            }
        }
        __syncthreads();                               // B4 (P reused next chunk)
    }

    if (tid < 32) inv_s[tid] = 1.0f / l_s[tid];
    __syncthreads();

    float i0 = inv_s[lq];
    float i1 = inv_s[16 + lq];
#pragma unroll
    for (int ct = 0; ct < 4; ++ct) {
#pragma unroll
        for (int qt = 0; qt < 2; ++qt) {
            float iv = qt ? i1 : i0;
            int qg = q0 + qt * 16 + lq;
            half4 h;
#pragma unroll
            for (int r = 0; r < 4; ++r) h[r] = (half_t)(acc[ct][qt][r] * iv);
            *(half4*)&attn_t[((size_t)n * HW + qg) * C2 + cb + ct * 16 + quad * 4] = h;
        }
    }
}

// ---------------------------------------------------------------------------
extern "C" void kernel_launch(void* const* d_in, const int* in_sizes, int n_in,
                              void* d_out, int out_size, void* d_ws, size_t ws_size,
                              hipStream_t stream)
{
    const float* x       = (const float*)d_in[0];
    const float* theta_w = (const float*)d_in[1];
    const float* theta_b = (const float*)d_in[2];
    const float* phi_w   = (const float*)d_in[3];
    const float* phi_b   = (const float*)d_in[4];
    const float* g_w     = (const float*)d_in[5];
    const float* g_b     = (const float*)d_in[6];
    const float* out_w   = (const float*)d_in[7];
    const float* out_b   = (const float*)d_in[8];
    const float* gamma   = (const float*)d_in[9];
    float* out = (float*)d_out;

    char* wsb = (char*)d_ws;
    half_t* x16t    = (half_t*)wsb;                    // 33,554,432 B
    half_t* attn_t  = (half_t*)wsb;                    // overlays x16t (dead by then)
    half_t* W16     = (half_t*)(wsb + 33554432);       // 655,360 B
    half_t* theta16 = (half_t*)(wsb + 34209792);       // 4,194,304 B
    half_t* phi16   = (half_t*)(wsb + 38404096);       // 1,048,576 B
    half_t* g16     = (half_t*)(wsb + 39452672);       // 4,194,304 B

    // 1) weights -> fp16
    cast_w_k<<<160, 256, 0, stream>>>(theta_w, phi_w, g_w, out_w, W16);
    // 2) x -> x16t [n][p][c] fp16
    cast_xt_k<<<dim3(512, NB), 256, 0, stream>>>(x, x16t);
    // 3) all projections in one launch (theta transposed; phi,g pooled)
    proj_k<<<dim3(32, 3, NB), 256, 0, stream>>>(
        W16, theta_b, phi_b, g_b, x16t, theta16, phi16, g16);
    // 4) flash attention -> attn_t fp16 [n][q][256]
    attn_flash_k<<<dim3(128, NB), 256, 0, stream>>>(theta16, phi16, g16, attn_t);
    // 5) final conv + gamma + residual -> out
    final_k<<<dim3(32, 4, NB), 256, 0, stream>>>(
        W16 + 196608, out_b, attn_t, out, x, gamma);
}

// Round 5
// 226.755 us; speedup vs baseline: 5.6111x; 1.1974x over previous
//
#include <hip/hip_runtime.h>
#include <hip/hip_bf16.h>
#include <cmath>

#define NB 8
#define HW 4096
#define PP 1024
#define C2 256

typedef _Float16 half_t;
typedef _Float16 half8 __attribute__((ext_vector_type(8)));
typedef _Float16 half4 __attribute__((ext_vector_type(4)));
typedef _Float16 half2t __attribute__((ext_vector_type(2)));
typedef float f32x4 __attribute__((ext_vector_type(4)));

// ---------------------------------------------------------------------------
// Cast all weights fp32 -> fp16 into W16: [theta 64x512 | phi 64x512 |
// g 256x512 | out 512x256]
// ---------------------------------------------------------------------------
__global__ __launch_bounds__(256) void cast_w_k(
    const float* __restrict__ tw, const float* __restrict__ pw,
    const float* __restrict__ gw, const float* __restrict__ ow,
    half_t* __restrict__ W16)
{
    int gid = blockIdx.x * 256 + threadIdx.x;
    size_t i0 = (size_t)gid * 8;
    const float* src; size_t off;
    if (i0 < 32768)       { src = tw; off = i0; }
    else if (i0 < 65536)  { src = pw; off = i0 - 32768; }
    else if (i0 < 196608) { src = gw; off = i0 - 65536; }
    else                  { src = ow; off = i0 - 196608; }
    float4 a = *(const float4*)&src[off];
    float4 b = *(const float4*)&src[off + 4];
    half8 h;
    h[0] = (half_t)a.x; h[1] = (half_t)a.y; h[2] = (half_t)a.z; h[3] = (half_t)a.w;
    h[4] = (half_t)b.x; h[5] = (half_t)b.y; h[6] = (half_t)b.z; h[7] = (half_t)b.w;
    *(half8*)&W16[i0] = h;
}

// ---------------------------------------------------------------------------
// Cast+transpose x: [n][512 c][4096 p] fp32 -> x16t [n][4096 p][512 c] fp16
// ---------------------------------------------------------------------------
__global__ __launch_bounds__(256) void cast_xt_k(const float* __restrict__ x,
                                                 half_t* __restrict__ x16t)
{
    __shared__ half_t T[64][72];
    const int tid = threadIdx.x;
    const int n = blockIdx.y;
    const int c0 = (blockIdx.x & 7) * 64;
    const int p0 = (blockIdx.x >> 3) * 64;

#pragma unroll
    for (int it = 0; it < 4; ++it) {
        int c = (tid >> 4) + 16 * it;
        int p4 = (tid & 15) * 4;
        float4 v = *(const float4*)&x[((size_t)n * 512 + c0 + c) * HW + p0 + p4];
        T[p4 + 0][c] = (half_t)v.x;
        T[p4 + 1][c] = (half_t)v.y;
        T[p4 + 2][c] = (half_t)v.z;
        T[p4 + 3][c] = (half_t)v.w;
    }
    __syncthreads();
#pragma unroll
    for (int it = 0; it < 2; ++it) {
        int p = (tid >> 3) + 32 * it;
        int ch = (tid & 7) * 8;
        half8 o = *(const half8*)&T[p][ch];
        *(half8*)&x16t[((size_t)n * HW + p0 + p) * 512 + c0 + ch] = o;
    }
}

// ---------------------------------------------------------------------------
// Fused projection GEMM, 128x128 tile, BK=64, 4 waves.
// y==0: A=[theta|phi]; theta transposed out, phi pooled+transposed.
// y==1,2: A=g rows; pooled 2x2 -> g16.
// ---------------------------------------------------------------------------
__global__ __launch_bounds__(256, 2) void proj_k(
    const half_t* __restrict__ W16, const float* __restrict__ theta_b,
    const float* __restrict__ phi_b, const float* __restrict__ g_b,
    const half_t* __restrict__ x16t, half_t* __restrict__ theta16,
    half_t* __restrict__ phi16, half_t* __restrict__ g16)
{
    __shared__ __align__(16) char smem[36864];
    half_t* As = (half_t*)smem;              // [128][72]
    half_t* Bs = (half_t*)(smem + 18432);    // [128][72]

    const int tid = threadIdx.x;
    const int wave = tid >> 6, lane = tid & 63;
    const int quad = lane >> 4, lq = lane & 15;
    const int wn = (wave & 1) * 64, wm = (wave >> 1) * 64;
    const int n = blockIdx.z;
    const int p0 = blockIdx.x * 128;
    const int ysel = blockIdx.y;

    const half_t* A16 = (ysel == 0) ? W16
                        : (W16 + 65536 + (size_t)(ysel - 1) * 128 * 512);

    const int srow = tid >> 3;
    const int schunk = (tid & 7) * 8;

    f32x4 acc[4][4];
#pragma unroll
    for (int mt = 0; mt < 4; ++mt)
#pragma unroll
        for (int nt = 0; nt < 4; ++nt)
            acc[mt][nt] = (f32x4){0.f, 0.f, 0.f, 0.f};

    for (int c0 = 0; c0 < 512; c0 += 64) {
#pragma unroll
        for (int i = 0; i < 4; ++i) {
            int r = srow + 32 * i;
            *(half8*)&As[r * 72 + schunk] =
                *(const half8*)&A16[(size_t)r * 512 + c0 + schunk];
        }
#pragma unroll
        for (int i = 0; i < 4; ++i) {
            int r = srow + 32 * i;
            *(half8*)&Bs[r * 72 + schunk] =
                *(const half8*)&x16t[((size_t)n * HW + p0 + r) * 512 + c0 + schunk];
        }
        __syncthreads();
#pragma unroll
        for (int ks = 0; ks < 2; ++ks) {
            half8 af[4], bf[4];
#pragma unroll
            for (int mt = 0; mt < 4; ++mt)
                af[mt] = *(const half8*)&As[(wm + mt * 16 + lq) * 72 + ks * 32 + quad * 8];
#pragma unroll
            for (int nt = 0; nt < 4; ++nt)
                bf[nt] = *(const half8*)&Bs[(wn + nt * 16 + lq) * 72 + ks * 32 + quad * 8];
#pragma unroll
            for (int mt = 0; mt < 4; ++mt)
#pragma unroll
                for (int nt = 0; nt < 4; ++nt)
                    acc[mt][nt] = __builtin_amdgcn_mfma_f32_16x16x32_f16(
                        af[mt], bf[nt], acc[mt][nt], 0, 0, 0);
        }
        __syncthreads();
    }

    if (ysel == 0) {
        half_t* Cs = (half_t*)smem;   // [64][136] phi C-tile
        if (wm == 0) {
#pragma unroll
            for (int mt = 0; mt < 4; ++mt) {
                float4 bv = *(const float4*)&theta_b[mt * 16 + quad * 4];
#pragma unroll
                for (int nt = 0; nt < 4; ++nt) {
                    int q = p0 + wn + nt * 16 + lq;
                    half4 h;
                    h[0] = (half_t)(acc[mt][nt][0] + bv.x);
                    h[1] = (half_t)(acc[mt][nt][1] + bv.y);
                    h[2] = (half_t)(acc[mt][nt][2] + bv.z);
                    h[3] = (half_t)(acc[mt][nt][3] + bv.w);
                    *(half4*)&theta16[((size_t)n * HW + q) * 64 + mt * 16 + quad * 4] = h;
                }
            }
        } else {
#pragma unroll
            for (int mt = 0; mt < 4; ++mt) {
                float4 bv = *(const float4*)&phi_b[mt * 16 + quad * 4];
#pragma unroll
                for (int nt = 0; nt < 4; ++nt) {
                    int col = wn + nt * 16 + lq;
                    int mr = mt * 16 + quad * 4;
                    Cs[(mr + 0) * 136 + col] = (half_t)(acc[mt][nt][0] + bv.x);
                    Cs[(mr + 1) * 136 + col] = (half_t)(acc[mt][nt][1] + bv.y);
                    Cs[(mr + 2) * 136 + col] = (half_t)(acc[mt][nt][2] + bv.z);
                    Cs[(mr + 3) * 136 + col] = (half_t)(acc[mt][nt][3] + bv.w);
                }
            }
        }
        __syncthreads();
        {
            int pw = tid >> 3;
            int kc = (tid & 7) * 8;
            half8 o;
#pragma unroll
            for (int jj = 0; jj < 8; ++jj) {
                int k = kc + jj;
                float v0 = (float)Cs[k * 136 + 2 * pw];
                float v1 = (float)Cs[k * 136 + 2 * pw + 1];
                float v2 = (float)Cs[k * 136 + 64 + 2 * pw];
                float v3 = (float)Cs[k * 136 + 65 + 2 * pw];
                o[jj] = (half_t)fmaxf(fmaxf(v0, v1), fmaxf(v2, v3));
            }
            *(half8*)&phi16[((size_t)n * PP + (p0 >> 7) * 32 + pw) * 64 + kc] = o;
        }
    } else {
        const int m0 = (ysel - 1) * 128;
        half_t* Cs = (half_t*)smem;   // [128][136]
#pragma unroll
        for (int mt = 0; mt < 4; ++mt) {
            float4 bv = *(const float4*)&g_b[m0 + wm + mt * 16 + quad * 4];
#pragma unroll
            for (int nt = 0; nt < 4; ++nt) {
                int col = wn + nt * 16 + lq;
                int mr = wm + mt * 16 + quad * 4;
                Cs[(mr + 0) * 136 + col] = (half_t)(acc[mt][nt][0] + bv.x);
                Cs[(mr + 1) * 136 + col] = (half_t)(acc[mt][nt][1] + bv.y);
                Cs[(mr + 2) * 136 + col] = (half_t)(acc[mt][nt][2] + bv.z);
                Cs[(mr + 3) * 136 + col] = (half_t)(acc[mt][nt][3] + bv.w);
            }
        }
        __syncthreads();
#pragma unroll
        for (int i = 0; i < 16; ++i) {
            int m = (tid >> 5) + 8 * i;
            int pw = tid & 31;
            float v0 = (float)Cs[m * 136 + 2 * pw];
            float v1 = (float)Cs[m * 136 + 2 * pw + 1];
            float v2 = (float)Cs[m * 136 + 64 + 2 * pw];
            float v3 = (float)Cs[m * 136 + 65 + 2 * pw];
            g16[((size_t)n * C2 + m0 + m) * PP + (p0 >> 7) * 32 + pw] =
                (half_t)fmaxf(fmaxf(v0, v1), fmaxf(v2, v3));
        }
    }
}

// ---------------------------------------------------------------------------
// Fused flash-attention + output conv. Block = (n, 64 q), 4 waves.
// 4 chunks of 256 p with online softmax; PV acc [256c x 64q] across waves;
// then O^T staged to LDS (reusing P) and 512x64x256 out-GEMM with fused
// bias/gamma/residual fp32 epilogue.
// ---------------------------------------------------------------------------
__global__ __launch_bounds__(256, 2) void attn_fused_k(
    const half_t* __restrict__ theta16,   // [n][4096][64]
    const half_t* __restrict__ phi16,     // [n][1024][64]
    const half_t* __restrict__ g16,       // [n][256][1024]
    const half_t* __restrict__ W16o,      // [512][256] fp16
    const float* __restrict__ out_b,      // [512]
    const float* __restrict__ x,          // [n][512][4096] fp32
    const float* __restrict__ gam,
    float* __restrict__ outF)             // [n][512][4096] fp32
{
    __shared__ half_t P[64][264];          // 33792 B (scores, then O^T)
    __shared__ float redM[4][64];
    __shared__ float redS[4][64];
    __shared__ float Ms[64], alpha_s[64], l_s[64], inv_s[64];

    const int tid  = threadIdx.x;
    const int wave = tid >> 6;
    const int lane = tid & 63;
    const int quad = lane >> 4;
    const int lq   = lane & 15;
    const int n  = blockIdx.y;
    const int q0 = blockIdx.x * 64;
    const int cb = wave * 64;

    const half_t* thN  = theta16 + ((size_t)n * HW + q0) * 64;
    const half_t* phiN = phi16 + (size_t)n * PP * 64;
    const half_t* gN   = g16 + (size_t)n * C2 * PP;

    if (tid < 64) { Ms[tid] = -1e30f; l_s[tid] = 0.f; }

    f32x4 acc[4][4];   // [ct][qt] : rows c, cols q
#pragma unroll
    for (int ct = 0; ct < 4; ++ct)
#pragma unroll
        for (int qt = 0; qt < 4; ++qt)
            acc[ct][qt] = (f32x4){0.f, 0.f, 0.f, 0.f};

    for (int chunk = 0; chunk < 4; ++chunk) {
        const int pch = chunk * 256;

        // --- E phase: wave covers 64 p of chunk ---
        half8 tb[4][2];
#pragma unroll
        for (int qt = 0; qt < 4; ++qt)
#pragma unroll
            for (int kb = 0; kb < 2; ++kb)
                tb[qt][kb] = *(const half8*)&thN[(size_t)(qt * 16 + lq) * 64 + kb * 32 + quad * 8];

        float mreg[4] = {-1e30f, -1e30f, -1e30f, -1e30f};
#pragma unroll
        for (int pt = 0; pt < 4; ++pt) {
            int pl = wave * 64 + pt * 16;
            const half_t* pr = &phiN[(size_t)(pch + pl + lq) * 64];
            half8 a0 = *(const half8*)&pr[quad * 8];
            half8 a1 = *(const half8*)&pr[32 + quad * 8];
#pragma unroll
            for (int qt = 0; qt < 4; ++qt) {
                f32x4 c = {0.f, 0.f, 0.f, 0.f};
                c = __builtin_amdgcn_mfma_f32_16x16x32_f16(a0, tb[qt][0], c, 0, 0, 0);
                c = __builtin_amdgcn_mfma_f32_16x16x32_f16(a1, tb[qt][1], c, 0, 0, 0);
                mreg[qt] = fmaxf(mreg[qt], fmaxf(fmaxf(c[0], c[1]), fmaxf(c[2], c[3])));
                half2t h0; h0[0] = (half_t)c[0]; h0[1] = (half_t)c[1];
                half2t h1; h1[0] = (half_t)c[2]; h1[1] = (half_t)c[3];
                *(half2t*)&P[qt * 16 + lq][pl + quad * 4]     = h0;
                *(half2t*)&P[qt * 16 + lq][pl + quad * 4 + 2] = h1;
            }
        }
#pragma unroll
        for (int qt = 0; qt < 4; ++qt) {
            float m = mreg[qt];
            m = fmaxf(m, __shfl_xor(m, 16));
            m = fmaxf(m, __shfl_xor(m, 32));
            mreg[qt] = m;
        }
        if (quad == 0) {
#pragma unroll
            for (int qt = 0; qt < 4; ++qt) redM[wave][qt * 16 + lq] = mreg[qt];
        }
        __syncthreads();                                   // B1

        if (tid < 64) {
            float cm = fmaxf(fmaxf(redM[0][tid], redM[1][tid]),
                             fmaxf(redM[2][tid], redM[3][tid]));
            float Mo = Ms[tid];
            float Mn = fmaxf(Mo, cm);
            alpha_s[tid] = __expf(Mo - Mn);
            Ms[tid] = Mn;
        }
        __syncthreads();                                   // B2

        // rescale O accumulators
        {
            float al[4];
#pragma unroll
            for (int qt = 0; qt < 4; ++qt) al[qt] = alpha_s[qt * 16 + lq];
#pragma unroll
            for (int ct = 0; ct < 4; ++ct)
#pragma unroll
                for (int qt = 0; qt < 4; ++qt)
#pragma unroll
                    for (int r = 0; r < 4; ++r) acc[ct][qt][r] *= al[qt];
        }

        // exp pass: thread = (q = tid&63, seg = wave)
        {
            int q = tid & 63, seg = tid >> 6;
            float M = Ms[q];
            float s = 0.f;
#pragma unroll
            for (int j = 0; j < 8; ++j) {
                half8 v = *(const half8*)&P[q][seg * 64 + j * 8];
                half8 o;
#pragma unroll
                for (int e = 0; e < 8; ++e) {
                    float f = __expf((float)v[e] - M);
                    s += f;
                    o[e] = (half_t)f;
                }
                *(half8*)&P[q][seg * 64 + j * 8] = o;
            }
            redS[seg][q] = s;
        }
        __syncthreads();                                   // B3

        if (tid < 64)
            l_s[tid] = l_s[tid] * alpha_s[tid]
                     + redS[0][tid] + redS[1][tid] + redS[2][tid] + redS[3][tid];

        // --- PV: wave covers c in [cb, cb+64); k over this chunk ---
#pragma unroll
        for (int kb = 0; kb < 8; ++kb) {
            half8 b[4];
#pragma unroll
            for (int qt = 0; qt < 4; ++qt)
                b[qt] = *(const half8*)&P[qt * 16 + lq][kb * 32 + quad * 8];
#pragma unroll
            for (int ct = 0; ct < 4; ++ct) {
                half8 a = *(const half8*)&gN[(size_t)(cb + ct * 16 + lq) * PP + pch + kb * 32 + quad * 8];
#pragma unroll
                for (int qt = 0; qt < 4; ++qt)
                    acc[ct][qt] = __builtin_amdgcn_mfma_f32_16x16x32_f16(a, b[qt], acc[ct][qt], 0, 0, 0);
            }
        }
        __syncthreads();                                   // B4
    }

    if (tid < 64) inv_s[tid] = 1.0f / l_s[tid];
    __syncthreads();

    // stage O^T fp16 into P as [q][c]
    {
        float iv[4];
#pragma unroll
        for (int qt = 0; qt < 4; ++qt) iv[qt] = inv_s[qt * 16 + lq];
#pragma unroll
        for (int ct = 0; ct < 4; ++ct) {
#pragma unroll
            for (int qt = 0; qt < 4; ++qt) {
                half2t h0, h1;
                h0[0] = (half_t)(acc[ct][qt][0] * iv[qt]);
                h0[1] = (half_t)(acc[ct][qt][1] * iv[qt]);
                h1[0] = (half_t)(acc[ct][qt][2] * iv[qt]);
                h1[1] = (half_t)(acc[ct][qt][3] * iv[qt]);
                *(half2t*)&P[qt * 16 + lq][cb + ct * 16 + quad * 4]     = h0;
                *(half2t*)&P[qt * 16 + lq][cb + ct * 16 + quad * 4 + 2] = h1;
            }
        }
    }
    __syncthreads();

    // out-GEMM: [512 m][64 q] over k=256, 2 m-passes
    const float g0 = gam[0];
#pragma unroll
    for (int pass = 0; pass < 2; ++pass) {
        const int mb = pass * 256 + wave * 64;
        f32x4 acc2[4][4];
#pragma unroll
        for (int mt = 0; mt < 4; ++mt)
#pragma unroll
            for (int qt = 0; qt < 4; ++qt)
                acc2[mt][qt] = (f32x4){0.f, 0.f, 0.f, 0.f};

#pragma unroll
        for (int kb = 0; kb < 8; ++kb) {
            half8 b[4];
#pragma unroll
            for (int qt = 0; qt < 4; ++qt)
                b[qt] = *(const half8*)&P[qt * 16 + lq][kb * 32 + quad * 8];
#pragma unroll
            for (int mt = 0; mt < 4; ++mt) {
                half8 a = *(const half8*)&W16o[(size_t)(mb + mt * 16 + lq) * 256 + kb * 32 + quad * 8];
#pragma unroll
                for (int qt = 0; qt < 4; ++qt)
                    acc2[mt][qt] = __builtin_amdgcn_mfma_f32_16x16x32_f16(a, b[qt], acc2[mt][qt], 0, 0, 0);
            }
        }

#pragma unroll
        for (int mt = 0; mt < 4; ++mt) {
            float4 bv = *(const float4*)&out_b[mb + mt * 16 + quad * 4];
#pragma unroll
            for (int qt = 0; qt < 4; ++qt) {
                int qg = q0 + qt * 16 + lq;
                int m = mb + mt * 16 + quad * 4;
                size_t off = ((size_t)(n * 512 + m)) * HW + qg;
                outF[off]          = g0 * (acc2[mt][qt][0] + bv.x) + x[off];
                outF[off + HW]     = g0 * (acc2[mt][qt][1] + bv.y) + x[off + HW];
                outF[off + 2*HW]   = g0 * (acc2[mt][qt][2] + bv.z) + x[off + 2*HW];
                outF[off + 3*HW]   = g0 * (acc2[mt][qt][3] + bv.w) + x[off + 3*HW];
            }
        }
    }
}

// ---------------------------------------------------------------------------
extern "C" void kernel_launch(void* const* d_in, const int* in_sizes, int n_in,
                              void* d_out, int out_size, void* d_ws, size_t ws_size,
                              hipStream_t stream)
{
    const float* x       = (const float*)d_in[0];
    const float* theta_w = (const float*)d_in[1];
    const float* theta_b = (const float*)d_in[2];
    const float* phi_w   = (const float*)d_in[3];
    const float* phi_b   = (const float*)d_in[4];
    const float* g_w     = (const float*)d_in[5];
    const float* g_b     = (const float*)d_in[6];
    const float* out_w   = (const float*)d_in[7];
    const float* out_b   = (const float*)d_in[8];
    const float* gamma   = (const float*)d_in[9];
    float* out = (float*)d_out;

    char* wsb = (char*)d_ws;
    half_t* x16t    = (half_t*)wsb;                    // 33,554,432 B
    half_t* W16     = (half_t*)(wsb + 33554432);       // 655,360 B
    half_t* theta16 = (half_t*)(wsb + 34209792);       // 4,194,304 B
    half_t* phi16   = (half_t*)(wsb + 38404096);       // 1,048,576 B
    half_t* g16     = (half_t*)(wsb + 39452672);       // 4,194,304 B

    // 1) weights -> fp16
    cast_w_k<<<160, 256, 0, stream>>>(theta_w, phi_w, g_w, out_w, W16);
    // 2) x -> x16t [n][p][c] fp16
    cast_xt_k<<<dim3(512, NB), 256, 0, stream>>>(x, x16t);
    // 3) all projections in one launch
    proj_k<<<dim3(32, 3, NB), 256, 0, stream>>>(
        W16, theta_b, phi_b, g_b, x16t, theta16, phi16, g16);
    // 4) fused flash attention + output conv + gamma + residual -> out
    attn_fused_k<<<dim3(64, NB), 256, 0, stream>>>(
        theta16, phi16, g16, W16 + 196608, out_b, x, gamma, out);
}